// Round 1
// baseline (1301.820 us; speedup 1.0000x reference)
//
#include <hip/hip_runtime.h>
#include <hip/hip_cooperative_groups.h>

namespace cg = cooperative_groups;

// HashGridEncoding: N=2^20 points, 12 levels, T=2^19 entries/level, F=2.
//
// Single persistent kernel, 1024 blocks x 256 threads x 4 points/thread.
// Levels processed in grid-lockstep (cooperative grid sync between levels)
// so each XCD L2 holds exactly one 4MB table at a time (same locality the
// old level-major dispatch had). Per-level results accumulate in registers
// as fp16 pairs scaled by 2^14 (identical numeric path to the previous
// passing kernel); final phase writes (N,24) fp32 directly as float4s.
// This deletes the 50MB ws intermediate + transpose kernel entirely and
// reads x once instead of 12 times.

constexpr int NPTS     = 1 << 20;
constexpr int NLEVELS  = 12;
constexpr unsigned T     = 1u << 19;
constexpr unsigned TMASK = T - 1u;
constexpr unsigned P1 = 2654435761u;
constexpr unsigned P2 = 805459861u;

constexpr float WS_SCALE     = 16384.0f;          // 2^14, exact
constexpr float WS_INV_SCALE = 1.0f / 16384.0f;

typedef float    vfloat2 __attribute__((ext_vector_type(2)));
typedef float    vfloat4 __attribute__((ext_vector_type(4)));
typedef _Float16 vhalf2  __attribute__((ext_vector_type(2)));

// floor(16 * 1.38^l) for l=0..11 (verified in fp64); constexpr so the fully
// unrolled level loop folds these to immediates (no constant-mem loads).
constexpr float k_res[NLEVELS] = {16.f, 22.f, 30.f, 42.f, 58.f, 80.f,
                                  110.f, 152.f, 210.f, 290.f, 400.f, 553.f};

__device__ __forceinline__ float2 encode_one_level(
    float px, float py, float pz, float r, const float2* __restrict__ tab)
{
    const float xs = px * r, ys = py * r, zs = pz * r;
    const float xf = floorf(xs), yf = floorf(ys), zf = floorf(zs);
    const float wx = xs - xf, wy = ys - yf, wz = zs - zf;
    const unsigned xi = (unsigned)xf, yi = (unsigned)yf, zi = (unsigned)zf;

    // Y hash component for the 4 (oy,oz) pairs; corner c = ox + 2*oy + 4*oz.
    unsigned Y[4];
#pragma unroll
    for (int j = 0; j < 4; ++j) {
        const unsigned oy = j & 1u, oz = (j >> 1) & 1u;
        Y[j] = ((yi + oy) * P1) ^ ((zi + oz) * P2);
    }

    float2 f[8];
    if ((xi & 1u) == 0u) {
        // even xi: corners (ox=0 -> h, ox=1 -> h^1) share one 16B-aligned pair
#pragma unroll
        for (int j = 0; j < 4; ++j) {
            const unsigned h = (xi ^ Y[j]) & TMASK;
            const vfloat4 q = *reinterpret_cast<const vfloat4*>(
                tab + (h & ~1u));
            const bool hi = (h & 1u) != 0u;   // entry h sits in high half?
            const float2 e_lo = make_float2(q.x, q.y);
            const float2 e_hi = make_float2(q.z, q.w);
            f[2 * j + 0] = hi ? e_hi : e_lo;  // ox=0 -> entry h
            f[2 * j + 1] = hi ? e_lo : e_hi;  // ox=1 -> entry h^1
        }
    } else {
#pragma unroll
        for (int j = 0; j < 4; ++j) {
            const unsigned h0 = (xi ^ Y[j]) & TMASK;
            const unsigned h1 = ((xi + 1u) ^ Y[j]) & TMASK;
            f[2 * j + 0] = tab[h0];
            f[2 * j + 1] = tab[h1];
        }
    }

    // accumulation order identical to reference (c = 0..7) -> bit-stable
    float f0 = 0.f, f1 = 0.f;
#pragma unroll
    for (int c = 0; c < 8; ++c) {
        const unsigned ox = c & 1u, oy = (c >> 1) & 1u, oz = (c >> 2) & 1u;
        const float w = (ox ? wx : 1.f - wx) *
                        (oy ? wy : 1.f - wy) *
                        (oz ? wz : 1.f - wz);
        f0 += w * f[c].x;
        f1 += w * f[c].y;
    }
    return make_float2(f0, f1);
}

// 4 points/thread, 1024 blocks x 256 threads = 2^20 points exactly.
// SYNC=true  -> launched cooperatively, grid.sync() between levels.
// SYNC=false -> normal launch, block-level barrier only (levels may drift
//               across blocks; correctness unaffected, only L2 locality).
template <bool SYNC>
__global__ __launch_bounds__(256, 4)
void hashgrid_coop_kernel(const float* __restrict__ x,
                          const float* __restrict__ tables,
                          float* __restrict__ out)
{
    const int tid = blockIdx.x * 256 + threadIdx.x;   // [0, 262144)
    const int n0  = tid * 4;                          // first of 4 points

    // 12 contiguous floats = coords of 4 points; three aligned float4 loads.
    const vfloat4* __restrict__ xv =
        reinterpret_cast<const vfloat4*>(x) + (size_t)tid * 3;
    const vfloat4 a = xv[0], b = xv[1], c = xv[2];
    const float px[4] = {a.x, a.w, b.z, c.y};
    const float py[4] = {a.y, b.x, b.w, c.z};
    const float pz[4] = {a.z, b.y, c.x, c.w};

    // Per-point per-level features, fp16 scaled by 2^14 (exact pow2).
    // Both loops fully unrolled -> all indices compile-time (stays in VGPRs).
    vhalf2 acc[4][NLEVELS];

#pragma unroll
    for (int l = 0; l < NLEVELS; ++l) {
        const float2* __restrict__ tab =
            reinterpret_cast<const float2*>(tables) + (size_t)l * T;
        const float r = k_res[l];
#pragma unroll
        for (int k = 0; k < 4; ++k) {
            const float2 f = encode_one_level(px[k], py[k], pz[k], r, tab);
            acc[k][l] = vhalf2{(_Float16)(f.x * WS_SCALE),
                               (_Float16)(f.y * WS_SCALE)};
        }
        if (l < NLEVELS - 1) {
            if constexpr (SYNC) {
                cg::this_grid().sync();     // keep all blocks on one level
            } else {
                __syncthreads();
            }
        }
    }

    // Direct (N,24) fp32 output: 6 float4 stores per point, 16B aligned.
#pragma unroll
    for (int k = 0; k < 4; ++k) {
        float* __restrict__ op = out + (size_t)(n0 + k) * 24;
#pragma unroll
        for (int i = 0; i < 6; ++i) {
            const vfloat4 v = {(float)acc[k][2 * i + 0].x * WS_INV_SCALE,
                               (float)acc[k][2 * i + 0].y * WS_INV_SCALE,
                               (float)acc[k][2 * i + 1].x * WS_INV_SCALE,
                               (float)acc[k][2 * i + 1].y * WS_INV_SCALE};
            __builtin_nontemporal_store(v, reinterpret_cast<vfloat4*>(op) + i);
        }
    }
}

extern "C" void kernel_launch(void* const* d_in, const int* in_sizes, int n_in,
                              void* d_out, int out_size, void* d_ws, size_t ws_size,
                              hipStream_t stream)
{
    const float* x      = reinterpret_cast<const float*>(d_in[0]);   // (N,3)
    const float* tables = reinterpret_cast<const float*>(d_in[1]);   // (12,T,2)
    float* out          = reinterpret_cast<float*>(d_out);           // (N,24)

    constexpr int GRID = NPTS / (256 * 4);   // 1024 blocks

    // Decide once: cooperative launch if supported and all 1024 blocks
    // can be co-resident (pure queries; graph-capture safe).
    static int mode = -1;
    if (mode < 0) {
        int dev = 0;
        (void)hipGetDevice(&dev);
        hipDeviceProp_t prop{};
        (void)hipGetDeviceProperties(&prop, dev);
        int nb = 0;
        (void)hipOccupancyMaxActiveBlocksPerMultiprocessor(
            &nb, hashgrid_coop_kernel<true>, 256, 0);
        const int cus = prop.multiProcessorCount > 0 ? prop.multiProcessorCount : 256;
        const int needed_per_cu = (GRID + cus - 1) / cus;   // 4 on MI355X
        mode = (prop.cooperativeLaunch != 0 && nb >= needed_per_cu) ? 1 : 0;
    }

    if (mode == 1) {
        void* args[] = {(void*)&x, (void*)&tables, (void*)&out};
        const hipError_t e = hipLaunchCooperativeKernel(
            reinterpret_cast<void*>(hashgrid_coop_kernel<true>),
            dim3(GRID), dim3(256), args, 0, stream);
        if (e == hipSuccess) return;
        mode = 0;   // cooperative path unavailable -> fall through
    }

    hashgrid_coop_kernel<false><<<dim3(GRID), dim3(256), 0, stream>>>(
        x, tables, out);
}

// Round 2
// 689.762 us; speedup vs baseline: 1.8873x; 1.8873x over previous
//
#include <hip/hip_runtime.h>

// HashGridEncoding: N=2^20 points, 12 levels, T=2^19 entries/level, F=2.
//
// Round-2 structure: spatial bucket-sort then gather.
// The level-gather kernel is divergent-request-throughput bound (~0.57
// line-requests/cycle/CU; VALUBusy 14.6%, HBM 16%). Requests are conserved
// under everything except LANE MERGING: if a wave's 64 lanes hold spatially
// adjacent points, levels 0-6 (res 16..110) hit the same table lines and the
// TA coalescer merges them into one request. So:
//   K1 key+hist -> K2 scan -> K3 scatter (sorted coords + sorted->orig perm)
//   K4 gather in sorted order (identical encode math, fp16 ws, coalesced)
//   K5 finish: coalesced ws reads in sorted order, scatter 96B/pt to out[orig]
// Per-point arithmetic is bit-identical to the proven kernel -> same absmax.
// Fallbacks: ws too small for sort -> proven 2-kernel path; tiny ws -> fused.

constexpr int NPTS     = 1 << 20;
constexpr int NLEVELS  = 12;
constexpr unsigned T     = 1u << 19;
constexpr unsigned TMASK = T - 1u;
constexpr unsigned P1 = 2654435761u;
constexpr unsigned P2 = 805459861u;

constexpr int NBUCK = 32 * 32 * 32;   // res-32 spatial buckets, 15-bit key

constexpr float WS_SCALE     = 16384.0f;          // 2^14, exact
constexpr float WS_INV_SCALE = 1.0f / 16384.0f;

typedef float    vfloat2 __attribute__((ext_vector_type(2)));
typedef float    vfloat4 __attribute__((ext_vector_type(4)));
typedef _Float16 vhalf2  __attribute__((ext_vector_type(2)));

// floor(16 * 1.38^l) for l=0..11 (verified in fp64)
__constant__ float c_res[NLEVELS] = {16.f, 22.f, 30.f, 42.f, 58.f, 80.f,
                                     110.f, 152.f, 210.f, 290.f, 400.f, 553.f};

__device__ __forceinline__ float2 encode_one_level(
    float px, float py, float pz, float r, const float2* __restrict__ tab)
{
    const float xs = px * r, ys = py * r, zs = pz * r;
    const float xf = floorf(xs), yf = floorf(ys), zf = floorf(zs);
    const float wx = xs - xf, wy = ys - yf, wz = zs - zf;
    const unsigned xi = (unsigned)xf, yi = (unsigned)yf, zi = (unsigned)zf;

    // Y hash component for the 4 (oy,oz) pairs; corner c = ox + 2*oy + 4*oz.
    unsigned Y[4];
#pragma unroll
    for (int j = 0; j < 4; ++j) {
        const unsigned oy = j & 1u, oz = (j >> 1) & 1u;
        Y[j] = ((yi + oy) * P1) ^ ((zi + oz) * P2);
    }

    float2 f[8];
    if ((xi & 1u) == 0u) {
        // even xi: corners (ox=0 -> h, ox=1 -> h^1) share one 16B-aligned pair
#pragma unroll
        for (int j = 0; j < 4; ++j) {
            const unsigned h = (xi ^ Y[j]) & TMASK;
            const vfloat4 q = *reinterpret_cast<const vfloat4*>(
                tab + (h & ~1u));
            const bool hi = (h & 1u) != 0u;   // entry h sits in high half?
            const float2 e_lo = make_float2(q.x, q.y);
            const float2 e_hi = make_float2(q.z, q.w);
            f[2 * j + 0] = hi ? e_hi : e_lo;  // ox=0 -> entry h
            f[2 * j + 1] = hi ? e_lo : e_hi;  // ox=1 -> entry h^1
        }
    } else {
#pragma unroll
        for (int j = 0; j < 4; ++j) {
            const unsigned h0 = (xi ^ Y[j]) & TMASK;
            const unsigned h1 = ((xi + 1u) ^ Y[j]) & TMASK;
            f[2 * j + 0] = tab[h0];
            f[2 * j + 1] = tab[h1];
        }
    }

    // accumulation order identical to reference (c = 0..7) -> bit-stable
    float f0 = 0.f, f1 = 0.f;
#pragma unroll
    for (int c = 0; c < 8; ++c) {
        const unsigned ox = c & 1u, oy = (c >> 1) & 1u, oz = (c >> 2) & 1u;
        const float w = (ox ? wx : 1.f - wx) *
                        (oy ? wy : 1.f - wy) *
                        (oz ? wz : 1.f - wz);
        f0 += w * f[c].x;
        f1 += w * f[c].y;
    }
    return make_float2(f0, f1);
}

// ---------------- sorted-path kernels ----------------

// K1: spatial bucket key (res-32 grid) + histogram.
__global__ __launch_bounds__(256)
void key_hist_kernel(const float* __restrict__ x,
                     unsigned* __restrict__ key,
                     unsigned* __restrict__ hist)
{
    const int n = blockIdx.x * 256 + threadIdx.x;
    const float px = x[3 * n + 0];
    const float py = x[3 * n + 1];
    const float pz = x[3 * n + 2];
    const unsigned bx = min((unsigned)(px * 32.0f), 31u);
    const unsigned by = min((unsigned)(py * 32.0f), 31u);
    const unsigned bz = min((unsigned)(pz * 32.0f), 31u);
    const unsigned k = (bx << 10) | (by << 5) | bz;
    key[n] = k;
    atomicAdd(&hist[k], 1u);
}

// K2: exclusive prefix sum of 32768 bucket counts -> cursor[].
// Single block, 1024 threads x 32 entries each.
__global__ __launch_bounds__(1024)
void scan_kernel(const unsigned* __restrict__ hist,
                 unsigned* __restrict__ cursor)
{
    __shared__ unsigned sblk[1024];
    const int t = threadIdx.x;
    const int base = t * 32;

    unsigned v[32];
    unsigned sum = 0;
#pragma unroll
    for (int i = 0; i < 32; ++i) {
        v[i] = hist[base + i];
        sum += v[i];
    }
    sblk[t] = sum;
    __syncthreads();

    // Hillis-Steele inclusive scan over the 1024 per-thread totals.
    for (int off = 1; off < 1024; off <<= 1) {
        const unsigned add = (t >= off) ? sblk[t - off] : 0u;
        __syncthreads();
        sblk[t] += add;
        __syncthreads();
    }
    unsigned acc = sblk[t] - sum;   // exclusive offset of this thread's chunk
#pragma unroll
    for (int i = 0; i < 32; ++i) {
        cursor[base + i] = acc;
        acc += v[i];
    }
}

// K3: scatter points into sorted order. Slot assignment within a bucket is
// race-ordered but the OUTPUT is independent of slot order (each point's
// result depends only on its own coords) -> deterministic final output.
__global__ __launch_bounds__(256)
void scatter_kernel(const float* __restrict__ x,
                    const unsigned* __restrict__ key,
                    unsigned* __restrict__ cursor,
                    float* __restrict__ xs,
                    unsigned* __restrict__ s2o)
{
    const int n = blockIdx.x * 256 + threadIdx.x;
    const unsigned k = key[n];
    const unsigned s = atomicAdd(&cursor[k], 1u);
    xs[3 * s + 0] = x[3 * n + 0];
    xs[3 * s + 1] = x[3 * n + 1];
    xs[3 * s + 2] = x[3 * n + 2];
    s2o[s] = n;
}

// K4: level-major gather over SORTED points. grid (NPTS/256, NLEVELS).
// Identical math to the proven level kernel; only the point order differs,
// so coarse-level table reads now merge within each wave.
__global__ __launch_bounds__(256, 8)
void gather_kernel(const float* __restrict__ xs,
                   const float* __restrict__ tables,
                   _Float16* __restrict__ ws)
{
    const int s = blockIdx.x * 256 + threadIdx.x;
    const int l = blockIdx.y;

    const float px = xs[3 * s + 0];
    const float py = xs[3 * s + 1];
    const float pz = xs[3 * s + 2];

    const float2* __restrict__ tab =
        reinterpret_cast<const float2*>(tables) + (size_t)l * T;

    const float2 f = encode_one_level(px, py, pz, c_res[l], tab);
    vhalf2 h = {(_Float16)(f.x * WS_SCALE), (_Float16)(f.y * WS_SCALE)};
    __builtin_nontemporal_store(
        h, reinterpret_cast<vhalf2*>(ws) + ((size_t)l * NPTS + s));
}

// K5: finish. Thread = sorted slot s: 12 coalesced fp16 reads, convert,
// write 96B contiguous to out[orig]. Writes are divergent 96B chunks
// (write-allocate cost ~1 line/pt, ~16us) -- far cheaper than divergent reads.
__global__ __launch_bounds__(256)
void finish_kernel(const _Float16* __restrict__ ws,
                   const unsigned* __restrict__ s2o,
                   float* __restrict__ out)
{
    const int s = blockIdx.x * 256 + threadIdx.x;
    const unsigned o = s2o[s];

    float vals[2 * NLEVELS];
#pragma unroll
    for (int l = 0; l < NLEVELS; ++l) {
        const vhalf2 h = __builtin_nontemporal_load(
            reinterpret_cast<const vhalf2*>(ws) + ((size_t)l * NPTS + s));
        vals[2 * l + 0] = (float)h.x * WS_INV_SCALE;
        vals[2 * l + 1] = (float)h.y * WS_INV_SCALE;
    }

    float* __restrict__ op = out + (size_t)o * 24;
#pragma unroll
    for (int i = 0; i < 6; ++i) {
        const vfloat4 v = {vals[4 * i + 0], vals[4 * i + 1],
                           vals[4 * i + 2], vals[4 * i + 3]};
        __builtin_nontemporal_store(v, reinterpret_cast<vfloat4*>(op) + i);
    }
}

// ---------------- proven fallback path (round-0, 381 us) ----------------

__global__ __launch_bounds__(256, 8)
void hashgrid_level_kernel(const float* __restrict__ x,
                           const float* __restrict__ tables,
                           _Float16* __restrict__ ws)
{
    const int n = blockIdx.x * 256 + threadIdx.x;
    const int l = blockIdx.y;

    const float px = x[3 * n + 0];
    const float py = x[3 * n + 1];
    const float pz = x[3 * n + 2];

    const float2* __restrict__ tab =
        reinterpret_cast<const float2*>(tables) + (size_t)l * T;

    const float2 f = encode_one_level(px, py, pz, c_res[l], tab);
    vhalf2 h = {(_Float16)(f.x * WS_SCALE), (_Float16)(f.y * WS_SCALE)};
    __builtin_nontemporal_store(
        h, reinterpret_cast<vhalf2*>(ws) + ((size_t)l * NPTS + n));
}

__global__ __launch_bounds__(256)
void hashgrid_transpose_kernel(const _Float16* __restrict__ ws,
                               float* __restrict__ out)
{
    __shared__ float lds[512 * 25];
    const int t = threadIdx.x;
    const int base = blockIdx.x * 512;

#pragma unroll
    for (int l = 0; l < NLEVELS; ++l) {
#pragma unroll
        for (int k = 0; k < 2; ++k) {
            const int p = t + 256 * k;
            const vhalf2 h = __builtin_nontemporal_load(
                reinterpret_cast<const vhalf2*>(ws) + ((size_t)l * NPTS + base + p));
            lds[p * 25 + 2 * l + 0] = (float)h.x * WS_INV_SCALE;
            lds[p * 25 + 2 * l + 1] = (float)h.y * WS_INV_SCALE;
        }
    }
    __syncthreads();

    float* __restrict__ ob = out + (size_t)base * 24;
#pragma unroll
    for (int i = 0; i < 12; ++i) {
        const int j  = i * 256 + t;
        const int f0 = 4 * j;
        const int p  = f0 / 24;
        const int c  = f0 % 24;
        vfloat4 v = {lds[p * 25 + c + 0], lds[p * 25 + c + 1],
                     lds[p * 25 + c + 2], lds[p * 25 + c + 3]};
        __builtin_nontemporal_store(v, reinterpret_cast<vfloat4*>(ob + f0));
    }
}

__global__ __launch_bounds__(256, 4)
void hashgrid_fused_kernel(const float* __restrict__ x,
                           const float* __restrict__ tables,
                           float* __restrict__ out)
{
    const int n = blockIdx.x * 256 + threadIdx.x;
    const float px = x[3 * n + 0];
    const float py = x[3 * n + 1];
    const float pz = x[3 * n + 2];

    float o[2 * NLEVELS];
#pragma unroll
    for (int l = 0; l < NLEVELS; ++l) {
        const float2* __restrict__ tab =
            reinterpret_cast<const float2*>(tables) + (size_t)l * T;
        const float2 f = encode_one_level(px, py, pz, c_res[l], tab);
        o[2 * l + 0] = f.x;
        o[2 * l + 1] = f.y;
    }
    float4* __restrict__ op = reinterpret_cast<float4*>(out + (size_t)n * 24);
#pragma unroll
    for (int i = 0; i < 6; ++i)
        op[i] = make_float4(o[4*i+0], o[4*i+1], o[4*i+2], o[4*i+3]);
}

// ---------------- launch ----------------

extern "C" void kernel_launch(void* const* d_in, const int* in_sizes, int n_in,
                              void* d_out, int out_size, void* d_ws, size_t ws_size,
                              hipStream_t stream)
{
    const float* x      = reinterpret_cast<const float*>(d_in[0]);   // (N,3)
    const float* tables = reinterpret_cast<const float*>(d_in[1]);   // (12,T,2)
    float* out          = reinterpret_cast<float*>(d_out);           // (N,24)

    // Workspace carve-up for the sorted path.
    const size_t SZ_WS16 = (size_t)NLEVELS * NPTS * 2 * sizeof(_Float16); // 48 MB
    const size_t SZ_XS   = (size_t)NPTS * 3 * sizeof(float);              // 12 MB
    const size_t SZ_S2O  = (size_t)NPTS * sizeof(unsigned);               //  4 MB
    const size_t SZ_KEY  = (size_t)NPTS * sizeof(unsigned);               //  4 MB
    const size_t SZ_H    = (size_t)NBUCK * sizeof(unsigned);              // 128 KB
    const size_t need_sorted = SZ_WS16 + SZ_XS + SZ_S2O + SZ_KEY + 2 * SZ_H;

    if (ws_size >= need_sorted) {
        char* p = reinterpret_cast<char*>(d_ws);
        _Float16* ws16   = reinterpret_cast<_Float16*>(p);  p += SZ_WS16;
        float*    xs     = reinterpret_cast<float*>(p);     p += SZ_XS;
        unsigned* s2o    = reinterpret_cast<unsigned*>(p);  p += SZ_S2O;
        unsigned* key    = reinterpret_cast<unsigned*>(p);  p += SZ_KEY;
        unsigned* hist   = reinterpret_cast<unsigned*>(p);  p += SZ_H;
        unsigned* cursor = reinterpret_cast<unsigned*>(p);

        hipMemsetAsync(hist, 0, SZ_H, stream);
        key_hist_kernel<<<NPTS / 256, 256, 0, stream>>>(x, key, hist);
        scan_kernel<<<1, 1024, 0, stream>>>(hist, cursor);
        scatter_kernel<<<NPTS / 256, 256, 0, stream>>>(x, key, cursor, xs, s2o);
        gather_kernel<<<dim3(NPTS / 256, NLEVELS), 256, 0, stream>>>(
            xs, tables, ws16);
        finish_kernel<<<NPTS / 256, 256, 0, stream>>>(ws16, s2o, out);
        return;
    }

    if (ws_size >= SZ_WS16) {
        _Float16* ws = reinterpret_cast<_Float16*>(d_ws);
        dim3 grid(NPTS / 256, NLEVELS);
        hashgrid_level_kernel<<<grid, 256, 0, stream>>>(x, tables, ws);
        hashgrid_transpose_kernel<<<NPTS / 512, 256, 0, stream>>>(ws, out);
        return;
    }

    hashgrid_fused_kernel<<<NPTS / 256, 256, 0, stream>>>(x, tables, out);
}

// Round 3
// 520.993 us; speedup vs baseline: 2.4987x; 1.3239x over previous
//
#include <hip/hip_runtime.h>

// HashGridEncoding: N=2^20 points, 12 levels, T=2^19 entries/level, F=2.
//
// Round-3: spatial sort kept; permutation moved from write-side to read-side.
//   K1 key_hist   : res-32 bucket histogram (no key array; recomputed later)
//   K2 scan       : exclusive prefix sum over 32768 buckets (1 block)
//   K3 scatter    : xs[s]=coords (scattered 12B), o2s[n]=s (COALESCED)
//   K4 gather     : level-major over sorted pts; writes TILED ws:
//                   ws_t[s/64][l][64] half2 -> 256B/wave/level, coalesced
//   K5 retile     : in-place LDS transpose of each 3KB tile to point-major
//                   (48B contiguous record per sorted point). Zero extra mem.
//   K6 finish     : thread n: s=o2s[n] (coalesced), read 48B record
//                   (scattered but L2/L3-resident), write out[n] coalesced.
// Round-2's finish scattered 96B HBM writes (WRITE_SIZE 235MB, 295us);
// now the only scattered traffic is cache-resident reads.
// Per-point arithmetic identical to the proven kernel -> same absmax.

constexpr int NPTS     = 1 << 20;
constexpr int NLEVELS  = 12;
constexpr unsigned T     = 1u << 19;
constexpr unsigned TMASK = T - 1u;
constexpr unsigned P1 = 2654435761u;
constexpr unsigned P2 = 805459861u;

constexpr int NBUCK = 32 * 32 * 32;   // res-32 spatial buckets, 15-bit key

constexpr float WS_SCALE     = 16384.0f;          // 2^14, exact
constexpr float WS_INV_SCALE = 1.0f / 16384.0f;

typedef float    vfloat2 __attribute__((ext_vector_type(2)));
typedef float    vfloat4 __attribute__((ext_vector_type(4)));
typedef _Float16 vhalf2  __attribute__((ext_vector_type(2)));
typedef unsigned vuint4  __attribute__((ext_vector_type(4)));

// floor(16 * 1.38^l) for l=0..11 (verified in fp64)
__constant__ float c_res[NLEVELS] = {16.f, 22.f, 30.f, 42.f, 58.f, 80.f,
                                     110.f, 152.f, 210.f, 290.f, 400.f, 553.f};

__device__ __forceinline__ float2 encode_one_level(
    float px, float py, float pz, float r, const float2* __restrict__ tab)
{
    const float xs = px * r, ys = py * r, zs = pz * r;
    const float xf = floorf(xs), yf = floorf(ys), zf = floorf(zs);
    const float wx = xs - xf, wy = ys - yf, wz = zs - zf;
    const unsigned xi = (unsigned)xf, yi = (unsigned)yf, zi = (unsigned)zf;

    unsigned Y[4];
#pragma unroll
    for (int j = 0; j < 4; ++j) {
        const unsigned oy = j & 1u, oz = (j >> 1) & 1u;
        Y[j] = ((yi + oy) * P1) ^ ((zi + oz) * P2);
    }

    float2 f[8];
    if ((xi & 1u) == 0u) {
        // even xi: corners (ox=0 -> h, ox=1 -> h^1) share one 16B-aligned pair
#pragma unroll
        for (int j = 0; j < 4; ++j) {
            const unsigned h = (xi ^ Y[j]) & TMASK;
            const vfloat4 q = *reinterpret_cast<const vfloat4*>(
                tab + (h & ~1u));
            const bool hi = (h & 1u) != 0u;
            const float2 e_lo = make_float2(q.x, q.y);
            const float2 e_hi = make_float2(q.z, q.w);
            f[2 * j + 0] = hi ? e_hi : e_lo;
            f[2 * j + 1] = hi ? e_lo : e_hi;
        }
    } else {
#pragma unroll
        for (int j = 0; j < 4; ++j) {
            const unsigned h0 = (xi ^ Y[j]) & TMASK;
            const unsigned h1 = ((xi + 1u) ^ Y[j]) & TMASK;
            f[2 * j + 0] = tab[h0];
            f[2 * j + 1] = tab[h1];
        }
    }

    float f0 = 0.f, f1 = 0.f;
#pragma unroll
    for (int c = 0; c < 8; ++c) {
        const unsigned ox = c & 1u, oy = (c >> 1) & 1u, oz = (c >> 2) & 1u;
        const float w = (ox ? wx : 1.f - wx) *
                        (oy ? wy : 1.f - wy) *
                        (oz ? wz : 1.f - wz);
        f0 += w * f[c].x;
        f1 += w * f[c].y;
    }
    return make_float2(f0, f1);
}

__device__ __forceinline__ unsigned bucket_of(float px, float py, float pz)
{
    const unsigned bx = min((unsigned)(px * 32.0f), 31u);
    const unsigned by = min((unsigned)(py * 32.0f), 31u);
    const unsigned bz = min((unsigned)(pz * 32.0f), 31u);
    return (bx << 10) | (by << 5) | bz;
}

// ---------------- sorted-path kernels ----------------

__global__ __launch_bounds__(256)
void key_hist_kernel(const float* __restrict__ x,
                     unsigned* __restrict__ hist)
{
    const int n = blockIdx.x * 256 + threadIdx.x;
    const unsigned k = bucket_of(x[3 * n + 0], x[3 * n + 1], x[3 * n + 2]);
    atomicAdd(&hist[k], 1u);
}

// Exclusive prefix sum of 32768 bucket counts. Single block, 1024 thr x 32.
__global__ __launch_bounds__(1024)
void scan_kernel(const unsigned* __restrict__ hist,
                 unsigned* __restrict__ cursor)
{
    __shared__ unsigned sblk[1024];
    const int t = threadIdx.x;
    const int base = t * 32;

    unsigned v[32];
    unsigned sum = 0;
#pragma unroll
    for (int i = 0; i < 32; ++i) {
        v[i] = hist[base + i];
        sum += v[i];
    }
    sblk[t] = sum;
    __syncthreads();

    for (int off = 1; off < 1024; off <<= 1) {
        const unsigned add = (t >= off) ? sblk[t - off] : 0u;
        __syncthreads();
        sblk[t] += add;
        __syncthreads();
    }
    unsigned acc = sblk[t] - sum;
#pragma unroll
    for (int i = 0; i < 32; ++i) {
        cursor[base + i] = acc;
        acc += v[i];
    }
}

// Scatter to sorted order. o2s[n]=s is a coalesced write (indexed by n).
// Slot order within a bucket is race-assigned, but each point's output
// depends only on its own coords -> deterministic final output.
__global__ __launch_bounds__(256)
void scatter_kernel(const float* __restrict__ x,
                    unsigned* __restrict__ cursor,
                    float* __restrict__ xs,
                    unsigned* __restrict__ o2s)
{
    const int n = blockIdx.x * 256 + threadIdx.x;
    const float px = x[3 * n + 0];
    const float py = x[3 * n + 1];
    const float pz = x[3 * n + 2];
    const unsigned k = bucket_of(px, py, pz);
    const unsigned s = atomicAdd(&cursor[k], 1u);
    xs[3 * s + 0] = px;
    xs[3 * s + 1] = py;
    xs[3 * s + 2] = pz;
    o2s[n] = s;
}

// Level-major gather over SORTED points; grid (NPTS/256, NLEVELS).
// Tiled ws: dword index (s/64)*768 + l*64 + (s%64)  [768 dw = 3KB tile]
// -> each wave writes 256B contiguous per level: fully coalesced.
__global__ __launch_bounds__(256, 8)
void gather_kernel(const float* __restrict__ xs,
                   const float* __restrict__ tables,
                   unsigned* __restrict__ ws_dw)
{
    const int s = blockIdx.x * 256 + threadIdx.x;
    const int l = blockIdx.y;

    const float px = xs[3 * s + 0];
    const float py = xs[3 * s + 1];
    const float pz = xs[3 * s + 2];

    const float2* __restrict__ tab =
        reinterpret_cast<const float2*>(tables) + (size_t)l * T;

    const float2 f = encode_one_level(px, py, pz, c_res[l], tab);
    const vhalf2 h = {(_Float16)(f.x * WS_SCALE), (_Float16)(f.y * WS_SCALE)};
    const size_t idx = (size_t)(s >> 6) * 768 + (unsigned)l * 64u + (s & 63);
    ws_dw[idx] = __builtin_bit_cast(unsigned, h);
}

// In-place per-tile transpose: level-major tiles -> point-major 48B records.
// Block = 16 tiles = 1024 points = 12288 dwords. LDS stride 13 (odd) keeps
// both phases conflict-free (<=2-3 way). Reads complete before the barrier,
// then writes land in the same chunk -> in-place is safe; blocks disjoint.
__global__ __launch_bounds__(256)
void retile_kernel(unsigned* __restrict__ ws_dw)
{
    __shared__ unsigned lds[1024 * 13];
    const int t = threadIdx.x;
    const size_t base = (size_t)blockIdx.x * 12288;

#pragma unroll
    for (int i = 0; i < 48; ++i) {
        const int g   = i * 256 + t;        // level-major dword in chunk
        const unsigned v = ws_dw[base + g];
        const int sbl = g / 768;            // local tile 0..15
        const int rem = g - sbl * 768;
        const int lv  = rem >> 6;           // 0..11
        const int pt  = rem & 63;
        lds[(sbl * 64 + pt) * 13 + lv] = v;
    }
    __syncthreads();

#pragma unroll
    for (int i = 0; i < 48; ++i) {
        const int j = i * 256 + t;          // point-major dword in chunk
        const int p = j / 12;
        const int c = j - p * 12;
        ws_dw[base + j] = lds[p * 13 + c];
    }
}

// finish-by-original: coalesced o2s read, scattered 48B record read
// (L2/L3-resident), fully coalesced out write.
__global__ __launch_bounds__(256)
void finish_kernel(const unsigned* __restrict__ ws_dw,
                   const unsigned* __restrict__ o2s,
                   float* __restrict__ out)
{
    const int n = blockIdx.x * 256 + threadIdx.x;
    const unsigned s = o2s[n];

    // record: 12 dwords at tile (s/64), slot (s%64): byte offset 48*s' -> 16B aligned
    const vuint4* __restrict__ rec = reinterpret_cast<const vuint4*>(
        ws_dw + (size_t)(s >> 6) * 768 + (size_t)(s & 63u) * 12);
    const vuint4 q0 = rec[0], q1 = rec[1], q2 = rec[2];
    const unsigned u[12] = {q0.x, q0.y, q0.z, q0.w,
                            q1.x, q1.y, q1.z, q1.w,
                            q2.x, q2.y, q2.z, q2.w};

    float vals[24];
#pragma unroll
    for (int l = 0; l < NLEVELS; ++l) {
        const vhalf2 h = __builtin_bit_cast(vhalf2, u[l]);
        vals[2 * l + 0] = (float)h.x * WS_INV_SCALE;
        vals[2 * l + 1] = (float)h.y * WS_INV_SCALE;
    }

    float* __restrict__ op = out + (size_t)n * 24;
#pragma unroll
    for (int i = 0; i < 6; ++i) {
        const vfloat4 v = {vals[4 * i + 0], vals[4 * i + 1],
                           vals[4 * i + 2], vals[4 * i + 3]};
        __builtin_nontemporal_store(v, reinterpret_cast<vfloat4*>(op) + i);
    }
}

// ---------------- proven fallback path (round-0, 381 us) ----------------

__global__ __launch_bounds__(256, 8)
void hashgrid_level_kernel(const float* __restrict__ x,
                           const float* __restrict__ tables,
                           _Float16* __restrict__ ws)
{
    const int n = blockIdx.x * 256 + threadIdx.x;
    const int l = blockIdx.y;

    const float px = x[3 * n + 0];
    const float py = x[3 * n + 1];
    const float pz = x[3 * n + 2];

    const float2* __restrict__ tab =
        reinterpret_cast<const float2*>(tables) + (size_t)l * T;

    const float2 f = encode_one_level(px, py, pz, c_res[l], tab);
    vhalf2 h = {(_Float16)(f.x * WS_SCALE), (_Float16)(f.y * WS_SCALE)};
    __builtin_nontemporal_store(
        h, reinterpret_cast<vhalf2*>(ws) + ((size_t)l * NPTS + n));
}

__global__ __launch_bounds__(256)
void hashgrid_transpose_kernel(const _Float16* __restrict__ ws,
                               float* __restrict__ out)
{
    __shared__ float lds[512 * 25];
    const int t = threadIdx.x;
    const int base = blockIdx.x * 512;

#pragma unroll
    for (int l = 0; l < NLEVELS; ++l) {
#pragma unroll
        for (int k = 0; k < 2; ++k) {
            const int p = t + 256 * k;
            const vhalf2 h = __builtin_nontemporal_load(
                reinterpret_cast<const vhalf2*>(ws) + ((size_t)l * NPTS + base + p));
            lds[p * 25 + 2 * l + 0] = (float)h.x * WS_INV_SCALE;
            lds[p * 25 + 2 * l + 1] = (float)h.y * WS_INV_SCALE;
        }
    }
    __syncthreads();

    float* __restrict__ ob = out + (size_t)base * 24;
#pragma unroll
    for (int i = 0; i < 12; ++i) {
        const int j  = i * 256 + t;
        const int f0 = 4 * j;
        const int p  = f0 / 24;
        const int c  = f0 % 24;
        vfloat4 v = {lds[p * 25 + c + 0], lds[p * 25 + c + 1],
                     lds[p * 25 + c + 2], lds[p * 25 + c + 3]};
        __builtin_nontemporal_store(v, reinterpret_cast<vfloat4*>(ob + f0));
    }
}

__global__ __launch_bounds__(256, 4)
void hashgrid_fused_kernel(const float* __restrict__ x,
                           const float* __restrict__ tables,
                           float* __restrict__ out)
{
    const int n = blockIdx.x * 256 + threadIdx.x;
    const float px = x[3 * n + 0];
    const float py = x[3 * n + 1];
    const float pz = x[3 * n + 2];

    float o[2 * NLEVELS];
#pragma unroll
    for (int l = 0; l < NLEVELS; ++l) {
        const float2* __restrict__ tab =
            reinterpret_cast<const float2*>(tables) + (size_t)l * T;
        const float2 f = encode_one_level(px, py, pz, c_res[l], tab);
        o[2 * l + 0] = f.x;
        o[2 * l + 1] = f.y;
    }
    float4* __restrict__ op = reinterpret_cast<float4*>(out + (size_t)n * 24);
#pragma unroll
    for (int i = 0; i < 6; ++i)
        op[i] = make_float4(o[4*i+0], o[4*i+1], o[4*i+2], o[4*i+3]);
}

// ---------------- launch ----------------

extern "C" void kernel_launch(void* const* d_in, const int* in_sizes, int n_in,
                              void* d_out, int out_size, void* d_ws, size_t ws_size,
                              hipStream_t stream)
{
    const float* x      = reinterpret_cast<const float*>(d_in[0]);   // (N,3)
    const float* tables = reinterpret_cast<const float*>(d_in[1]);   // (12,T,2)
    float* out          = reinterpret_cast<float*>(d_out);           // (N,24)

    const size_t SZ_WS  = (size_t)NPTS * NLEVELS * 4;        // 48 MB tiled ws
    const size_t SZ_XS  = (size_t)NPTS * 3 * sizeof(float);  // 12 MB
    const size_t SZ_O2S = (size_t)NPTS * sizeof(unsigned);   //  4 MB
    const size_t SZ_H   = (size_t)NBUCK * sizeof(unsigned);  // 128 KB
    const size_t need_sorted = SZ_WS + SZ_XS + SZ_O2S + 2 * SZ_H;   // 64.3 MB

    if (ws_size >= need_sorted) {
        char* p = reinterpret_cast<char*>(d_ws);
        unsigned* ws_dw  = reinterpret_cast<unsigned*>(p);  p += SZ_WS;
        float*    xs     = reinterpret_cast<float*>(p);     p += SZ_XS;
        unsigned* o2s    = reinterpret_cast<unsigned*>(p);  p += SZ_O2S;
        unsigned* hist   = reinterpret_cast<unsigned*>(p);  p += SZ_H;
        unsigned* cursor = reinterpret_cast<unsigned*>(p);

        hipMemsetAsync(hist, 0, SZ_H, stream);
        key_hist_kernel<<<NPTS / 256, 256, 0, stream>>>(x, hist);
        scan_kernel<<<1, 1024, 0, stream>>>(hist, cursor);
        scatter_kernel<<<NPTS / 256, 256, 0, stream>>>(x, cursor, xs, o2s);
        gather_kernel<<<dim3(NPTS / 256, NLEVELS), 256, 0, stream>>>(
            xs, tables, ws_dw);
        retile_kernel<<<NPTS / 1024, 256, 0, stream>>>(ws_dw);
        finish_kernel<<<NPTS / 256, 256, 0, stream>>>(ws_dw, o2s, out);
        return;
    }

    if (ws_size >= (size_t)NLEVELS * NPTS * 2 * sizeof(_Float16)) {
        _Float16* ws = reinterpret_cast<_Float16*>(d_ws);
        dim3 grid(NPTS / 256, NLEVELS);
        hashgrid_level_kernel<<<grid, 256, 0, stream>>>(x, tables, ws);
        hashgrid_transpose_kernel<<<NPTS / 512, 256, 0, stream>>>(ws, out);
        return;
    }

    hashgrid_fused_kernel<<<NPTS / 256, 256, 0, stream>>>(x, tables, out);
}